// Round 11
// baseline (2276.269 us; speedup 1.0000x reference)
//
#include <hip/hip_runtime.h>
#include <hip/hip_bf16.h>

typedef __hip_bfloat16 bf16;

#define NN 192      // nodes per group
#define NG 8        // groups
#define BB 1536     // batch
#define EHID 256
#define DH 320      // decoder hidden
#define PRED 12
#define STRD 192    // row stride (floats). Swizzled layout -> no pad needed.
#define ATILE (NN*STRD)   // 36864 floats per group

// Swizzled element offset inside one A tile.
__device__ __forceinline__ int aoffc(int r, int c){
  int c4 = c >> 2;
  int s = (c4 & ~7) | ((c4 + 3*r) & 7);
  return r*STRD + (s << 2) + (c & 3);
}

#define WAVE_SYNC() do { asm volatile("" ::: "memory"); __builtin_amdgcn_wave_barrier(); } while (0)

__device__ __forceinline__ float waveSum(float v){
#pragma unroll
  for (int o = 32; o > 0; o >>= 1) v += __shfl_down(v, o);
  return v;
}
__device__ __forceinline__ double waveSumD(double v){
#pragma unroll
  for (int o = 32; o > 0; o >>= 1) v += __shfl_down(v, o);
  return v;
}
__device__ __forceinline__ float waveAllSum(float v){
#pragma unroll
  for (int o = 32; o > 0; o >>= 1) v += __shfl_xor(v, o);
  return v;
}
__device__ __forceinline__ double waveAllSumD(double v){
#pragma unroll
  for (int o = 32; o > 0; o >>= 1) v += __shfl_xor(v, o);
  return v;
}

__device__ __forceinline__ double blockSumD(double v, double* red){
  int lane = threadIdx.x & 63, wid = threadIdx.x >> 6, nw = (int)blockDim.x >> 6;
  double s = waveSumD(v);
  __syncthreads();
  if (lane == 0) red[wid] = s;
  __syncthreads();
  if (wid == 0){
    double t = (lane < nw) ? red[lane] : 0.0;
    t = waveSumD(t);
    if (lane == 0) red[0] = t;
  }
  __syncthreads();
  return red[0];
}

// ---------------- dtype probe + conversion ----------------

__global__ void k_zero_int(int* __restrict__ p, int n){
  int i = blockIdx.x*blockDim.x + threadIdx.x;
  if (i < n) p[i] = 0;
}

__global__ void k_probe(const unsigned short* __restrict__ src, int n, int* __restrict__ cnt){
  int tid = blockIdx.x*blockDim.x + threadIdx.x;
  int stride = gridDim.x*blockDim.x;
  int bad = 0;
  for (int j = tid; j < n; j += stride){
    float v = __uint_as_float(((unsigned int)src[j]) << 16);
    if (!(fabsf(v) < 100.f)) bad++;
  }
#pragma unroll
  for (int o = 32; o > 0; o >>= 1) bad += __shfl_down(bad, o);
  if ((threadIdx.x & 63) == 0 && bad > 0) atomicAdd(cnt, bad);
}
__global__ void k_flag(const int* __restrict__ cnt, int* __restrict__ flag){
  *flag = (*cnt > 4096) ? 1 : 0;        // 1 = inputs are fp32, 0 = bf16
}

struct CvtArgs {
  const void* src[20];
  float*      dst[20];
  int         n[20];
};

__global__ void k_convert(CvtArgs a, const int* __restrict__ flag){
  int id = blockIdx.y;
  int n = a.n[id];
  float* d = a.dst[id];
  int t = blockIdx.x*blockDim.x + threadIdx.x;
  int stride = gridDim.x*blockDim.x;
  if (*flag == 0){
    const bf16* s = (const bf16*)a.src[id];
    for (int j = t; j < n; j += stride) d[j] = __bfloat162float(s[j]);
  } else {
    const float* s = (const float*)a.src[id];
    for (int j = t; j < n; j += stride) d[j] = s[j];
  }
}

// permuted weight convert: dst[(4*j+q)*K + kk] = src[(q*H+j)*K + kk]
__global__ void k_permw(const void* __restrict__ src, float* __restrict__ dst,
                        int H, int K, const int* __restrict__ flag){
  int idx = blockIdx.x*blockDim.x + threadIdx.x;
  int n = 4*H*K;
  if (idx >= n) return;
  int r = idx / K, kk = idx - r*K;
  int j = r >> 2, q = r & 3;
  int si = (q*H + j)*K + kk;
  float v;
  if (*flag == 0) v = __bfloat162float(((const bf16*)src)[si]);
  else            v = ((const float*)src)[si];
  dst[idx] = v;
}

// permuted bias sum: dst[4j+q] = b1[q*H+j] + b2[q*H+j]
__global__ void k_permb(const void* __restrict__ b1, const void* __restrict__ b2,
                        float* __restrict__ dst, int H, const int* __restrict__ flag){
  int r = blockIdx.x*blockDim.x + threadIdx.x;
  if (r >= 4*H) return;
  int j = r >> 2, q = r & 3;
  int si = q*H + j;
  float v1, v2;
  if (*flag == 0){
    v1 = __bfloat162float(((const bf16*)b1)[si]);
    v2 = __bfloat162float(((const bf16*)b2)[si]);
  } else {
    v1 = ((const float*)b1)[si];
    v2 = ((const float*)b2)[si];
  }
  dst[r] = v1 + v2;
}

// ---------------- small kernels ----------------

// fused decoder init: h = [henc | z], c = 0, traj = t7  (3 launches -> 1)
__global__ void k_decinit(const float* __restrict__ henc, const float* __restrict__ z,
                          const float* __restrict__ t7, float* __restrict__ h,
                          float* __restrict__ c, float* __restrict__ traj){
  int idx = blockIdx.x*blockDim.x + threadIdx.x;
  if (idx < BB*2) traj[idx] = t7[idx];
  if (idx >= BB*DH) return;
  int b = idx / DH, j = idx - b*DH;
  h[idx] = (j < EHID) ? henc[b*EHID + j] : z[(b/NN)*64 + (j - EHID)];
  c[idx] = 0.f;
}

// FUSED embed + gates-GEMM + LSTM pointwise (+ inline outproj via partials).
// Weights Wp [4H][64], Up [4H][H] interleaved: row 4j+q = gate q of state j.
// read_part: traj values come from summing per-column-block partials (+bias);
//            block x==0 also writes d_out[step-1].
// write_part: epilogue reduces h·Wout over the block's 16 states (shfl over tx)
//             and writes part[xblk][row][2] (atomic-free).
__global__ __launch_bounds__(256) void k_gates_lstm(
    const float* __restrict__ traj2,   // [BB][2] input positions (read_part==0)
    const float* __restrict__ Wemb, const float* __restrict__ bemb,
    const float* __restrict__ Wp, const float* __restrict__ Up,
    const float* __restrict__ bsum,
    const float* __restrict__ hin, float* __restrict__ hout,
    float* __restrict__ cst, int H,
    int read_part, int write_part,
    float* __restrict__ part, const float* __restrict__ Wout,
    const float* __restrict__ bout,
    void* __restrict__ outbase, int step, const int* __restrict__ flag){
  __shared__ __align__(16) float inpT[64][68];   // embed tile, [k][row]
  __shared__ __align__(16) float As[32][68];
  __shared__ __align__(16) float Ws[32][68];
  __shared__ float xs[64], ys[64];
  int tid = threadIdx.x;
  int tx = tid & 15, ty = tid >> 4;
  int n0 = blockIdx.x * 64, m0 = blockIdx.y * 64;

  // prologue: xy for 64 rows (from traj2 or summed partials), optional d_out
  if (tid < 128){
    int r = tid >> 1, comp = tid & 1;
    float v;
    if (read_part){
      float sacc = bout[comp];
      int nxb = gridDim.x;
      for (int b = 0; b < nxb; ++b)
        sacc += part[((size_t)b*BB + m0 + r)*2 + comp];
      v = sacc;
      if (blockIdx.x == 0){
        size_t oidx = (size_t)(step-1)*BB*2 + (size_t)(m0+r)*2 + comp;
        if (*flag == 0) ((bf16*)outbase)[oidx] = __float2bfloat16(sacc);
        else            ((float*)outbase)[oidx] = sacc;
      }
    } else {
      v = traj2[(size_t)(m0 + r)*2 + comp];
    }
    if (comp == 0) xs[r] = v; else ys[r] = v;
  }
  __syncthreads();

  // embed tile: inpT[e][r] = relu(Wemb[e]·xy_r + bemb[e])
  {
    int r = tid & 63;
    float x = xs[r], y = ys[r];
    for (int e = tid >> 6; e < 64; e += 4){
      float v = Wemb[e*2]*x + Wemb[e*2+1]*y + bemb[e];
      inpT[e][r] = v > 0.f ? v : 0.f;
    }
  }
  float acc[4][4] = {};
  // phase 0: K=64 (embed) from inpT
  for (int k0 = 0; k0 < 64; k0 += 32){
    {
      int am = tid >> 2, ak = (tid & 3) * 8;
      const float* srcW = Wp + (size_t)(n0+am)*64 + k0 + ak;
      float4 w0 = *(const float4*)(srcW);
      float4 w1 = *(const float4*)(srcW+4);
      Ws[ak+0][am]=w0.x; Ws[ak+1][am]=w0.y; Ws[ak+2][am]=w0.z; Ws[ak+3][am]=w0.w;
      Ws[ak+4][am]=w1.x; Ws[ak+5][am]=w1.y; Ws[ak+6][am]=w1.z; Ws[ak+7][am]=w1.w;
    }
    __syncthreads();
#pragma unroll
    for (int k = 0; k < 32; ++k){
      float4 a0 = *(const float4*)&inpT[k0+k][ty*4];
      float4 b0 = *(const float4*)&Ws[k][tx*4];
      float av[4] = {a0.x, a0.y, a0.z, a0.w};
      float bv[4] = {b0.x, b0.y, b0.z, b0.w};
#pragma unroll
      for (int i = 0; i < 4; ++i)
#pragma unroll
        for (int j = 0; j < 4; ++j)
          acc[i][j] += av[i]*bv[j];
    }
    __syncthreads();
  }
  // phase 1: K=H (recurrent)
  for (int k0 = 0; k0 < H; k0 += 32){
    {
      int am = tid >> 2, ak = (tid & 3) * 8;
      const float* srcA = hin + (size_t)(m0+am)*H + k0 + ak;
      float4 f0 = *(const float4*)(srcA);
      float4 f1 = *(const float4*)(srcA+4);
      As[ak+0][am]=f0.x; As[ak+1][am]=f0.y; As[ak+2][am]=f0.z; As[ak+3][am]=f0.w;
      As[ak+4][am]=f1.x; As[ak+5][am]=f1.y; As[ak+6][am]=f1.z; As[ak+7][am]=f1.w;
      const float* srcW = Up + (size_t)(n0+am)*H + k0 + ak;
      float4 w0 = *(const float4*)(srcW);
      float4 w1 = *(const float4*)(srcW+4);
      Ws[ak+0][am]=w0.x; Ws[ak+1][am]=w0.y; Ws[ak+2][am]=w0.z; Ws[ak+3][am]=w0.w;
      Ws[ak+4][am]=w1.x; Ws[ak+5][am]=w1.y; Ws[ak+6][am]=w1.z; Ws[ak+7][am]=w1.w;
    }
    __syncthreads();
#pragma unroll
    for (int k = 0; k < 32; ++k){
      float4 a0 = *(const float4*)&As[k][ty*4];
      float4 b0 = *(const float4*)&Ws[k][tx*4];
      float av[4] = {a0.x, a0.y, a0.z, a0.w};
      float bv[4] = {b0.x, b0.y, b0.z, b0.w};
#pragma unroll
      for (int i = 0; i < 4; ++i)
#pragma unroll
        for (int j = 0; j < 4; ++j)
          acc[i][j] += av[i]*bv[j];
    }
    __syncthreads();
  }
  // epilogue: cols n0+tx*4+{0..3} = (i,f,g,o) of state s
  int s = (n0 >> 2) + tx;
  float4 bq = *(const float4*)&bsum[n0 + tx*4];
  float hv4[4];
#pragma unroll
  for (int i2 = 0; i2 < 4; ++i2){
    int row = m0 + ty*4 + i2;
    float gi = acc[i2][0] + bq.x;
    float gf = acc[i2][1] + bq.y;
    float gg = acc[i2][2] + bq.z;
    float go = acc[i2][3] + bq.w;
    float si = 1.f/(1.f+expf(-gi));
    float sf = 1.f/(1.f+expf(-gf));
    float so = 1.f/(1.f+expf(-go));
    size_t cidx = (size_t)row*H + s;
    float cc = sf*cst[cidx] + si*tanhf(gg);
    cst[cidx] = cc;
    float hv = so*tanhf(cc);
    hout[cidx] = hv;
    hv4[i2] = hv;
  }
  if (write_part){
    float w0s = Wout[s], w1s = Wout[DH + s];
#pragma unroll
    for (int i2 = 0; i2 < 4; ++i2){
      float p0 = hv4[i2]*w0s, p1 = hv4[i2]*w1s;
#pragma unroll
      for (int o = 1; o < 16; o <<= 1){
        p0 += __shfl_xor(p0, o);
        p1 += __shfl_xor(p1, o);
      }
      if (tx == 0){
        int row = m0 + ty*4 + i2;
        part[((size_t)blockIdx.x*BB + row)*2 + 0] = p0;
        part[((size_t)blockIdx.x*BB + row)*2 + 1] = p1;
      }
    }
  }
}

// final output slice (step PRED-1): sum partials + bias -> d_out
__global__ void k_finout(const float* __restrict__ part, const float* __restrict__ bout,
                         int nxb, void* __restrict__ outbase, int step,
                         const int* __restrict__ flag){
  int idx = blockIdx.x*blockDim.x + threadIdx.x;
  if (idx >= BB*2) return;
  int row = idx >> 1, comp = idx & 1;
  float sacc = bout[comp];
  for (int b = 0; b < nxb; ++b)
    sacc += part[((size_t)b*BB + row)*2 + comp];
  size_t oidx = (size_t)step*BB*2 + idx;
  if (*flag == 0) ((bf16*)outbase)[oidx] = __float2bfloat16(sacc);
  else            ((float*)outbase)[oidx] = sacc;
}

// ---------------- signed-graph kernels ----------------

__global__ void k_sg_emb(const float* __restrict__ h, const float* __restrict__ Wne,
                         const float* __restrict__ bne, const float* __restrict__ Watt,
                         double* __restrict__ sself, double* __restrict__ sother){
  int node = blockIdx.x, e = threadIdx.x;
  const float* hb = h + (size_t)node*DH;
  double acc = (double)bne[e];
  for (int k = 0; k < DH; ++k) acc += (double)hb[k]*(double)Wne[e*DH+k];
  double po = acc * (double)Watt[e];
  double ps = acc * (double)Watt[64+e];
  po = waveSumD(po); ps = waveSumD(ps);
  if (e == 0){ sother[node] = po; sself[node] = ps; }
}

__global__ void k_sg_edgecol(const double* __restrict__ sself, const double* __restrict__ sother,
                             const float* __restrict__ batt, double* __restrict__ edge){
  int g = blockIdx.x, j = threadIdx.x;
  const double* ss = sself + g*NN;
  double bb = (double)batt[0];
  double sj = sother[g*NN + j];
  double m = -1e300;
  for (int i = 0; i < NN; ++i){
    double e = ss[i] + sj + bb; e = e > 0.0 ? e : 0.2*e;
    m = fmax(m, e);
  }
  double sum = 0.0;
  for (int i = 0; i < NN; ++i){
    double e = ss[i] + sj + bb; e = e > 0.0 ? e : 0.2*e;
    sum += exp(e - m);
  }
  double* E = edge + (size_t)g*NN*NN;
  for (int i = 0; i < NN; ++i){
    double e = ss[i] + sj + bb; e = e > 0.0 ? e : 0.2*e;
    E[i*NN + j] = exp(e - m)/sum;
  }
}

// fused: esym row build + row-sum (sym + dsum in one pass). block = (g,i) row.
__global__ void k_sg_symdsum(const double* __restrict__ edge, double* __restrict__ esym,
                             double* __restrict__ darr){
  int gi = blockIdx.x;                 // 0..NG*NN-1
  int g = gi / NN, i = gi - g*NN;
  int j = threadIdx.x;                 // 192 threads = 3 waves
  __shared__ double red[4];
  const double* E = edge + (size_t)g*NN*NN;
  double w = (i <= j) ? E[(size_t)i*NN + j] : E[(size_t)j*NN + i];
  esym[(size_t)g*NN*NN + (size_t)i*NN + j] = w;
  double sres = waveSumD(w);
  int lane = j & 63, w2 = j >> 6;
  if (lane == 0) red[w2] = sres;
  __syncthreads();
  if (j == 0) darr[gi] = fmax(red[0] + red[1] + red[2], 1e-300);
}

__global__ void k_sg_lsym(const double* __restrict__ esym, const double* __restrict__ darr,
                          float* __restrict__ Afull){
  int idx = blockIdx.x*blockDim.x + threadIdx.x;
  if (idx >= NG*NN*NN) return;
  int g = idx / (NN*NN), r = idx - g*NN*NN;
  int i = r / NN, j = r - i*NN;
  double w = esym[idx];
  double lij = (i == j) ? (darr[g*NN+i] - w) : (-w);
  Afull[(size_t)g*ATILE + aoffc(i, j)] =
      (float)(lij / (sqrt(darr[g*NN+i])*sqrt(darr[g*NN+j])));
}

// LDS-resident swizzled fp32 Householder tridiag, TLP version (round-4 verbatim,
// best measured: 1034-1038 us):
//  * 1024 threads = 4 column-teams x 256 row-threads (16 waves, 4/SIMD)
//  * matvec: per-team partials into pp4[team*NN+i] (stride-1, conflict-free)
//  * rank-2: each team updates its column blocks
//  * 6 barriers / iteration; barrier-free single-wave tail for m <= 64
//  * fp64 Sturm bisection + serial LU inverse iteration (wave 0)
//  * register back-transform + Gram-Schmidt on wave 0 (3 rows/lane)
// dynamic LDS = 159248 B.
__global__ __launch_bounds__(1024) void k_sg_eigen(const float* __restrict__ Afull,
                                                   const double* __restrict__ darr,
                                                   double* __restrict__ v1out){
  extern __shared__ unsigned char ldsraw[];
  float*  A     = (float*)ldsraw;                       // ATILE fp32 (147456 B)
  double* dd    = (double*)(ldsraw + 147456);           // NN
  double* ee    = dd + NN;                              // NN
  double* yv    = ee + NN;                              // NN (block-phase: aliased by pp4)
  double* lu_d  = yv + NN;                              // NN (block-phase: aliased by pp4)
  double* lu_du = lu_d + NN;                            // NN
  double* lu_du2= lu_du + NN;                           // NN   (ends 156672 B)
  double* redA  = lu_du2 + NN;                          // 16   (-> 156800 B)
  double* redB  = redA + 16;                            // 16   (-> 156928 B)
  double* salpha= redB + 16;                            // 1    (-> 156936 B)
  float*  uu    = (float*)(ldsraw + 156944);            // NN fp32 (-> 157712 B)
  float*  ww    = uu + NN;                              // NN fp32 (-> 158480 B)
  int*    lu_piv= (int*)(ww + NN);                      // NN int  (-> 159248 B)
  float*  pp4   = (float*)yv;                           // alias: 4*NN fp32 over yv+lu_d
  double* lu_dl = (double*)uu;                          // alias (uu+ww dead in LU)

  int g = blockIdx.x, tid = threadIdx.x;
  int lane = tid & 63, wid = tid >> 6;   // 16 waves
  int rtid = tid & 255, team = tid >> 8; // 4 teams x 256 row-threads

  const float* src = Afull + (size_t)g*ATILE;
  for (int t = tid*4; t < ATILE; t += 4096) *(float4*)&A[t] = *(const float4*)&src[t];
  __syncthreads();

  // ---- block-wide Householder, m > 64 (k = 0..NN-66) ----
  for (int k = 0; k < NN-65; ++k){
    int m = NN-1-k;
    int i = k+1+rtid;
    float x = 0.f;
    if (rtid < m) x = A[aoffc(i, k)];    // all teams read (same col -> broadcast)
    if (tid == 0) *salpha = (double)x;
    if (team == 0){
      float part = (rtid > 0 && rtid < m) ? x*x : 0.f;
      part = waveSum(part);
      if (lane == 0) redA[wid] = (double)part;   // wid 0..3
    }
    __syncthreads();                                   // B1: sigma + alpha ready
    double sigma = redA[0] + redA[1] + redA[2] + redA[3];
    double alpha = *salpha;
    double beta, tau, scale;
    if (sigma <= 1e-30){ tau = 0.0; beta = alpha; scale = 0.0; }
    else {
      beta = -copysign(sqrt(alpha*alpha + sigma), alpha);
      tau = (beta - alpha)/beta;
      scale = 1.0/(alpha - beta);
    }
    float tau_f = (float)tau, scale_f = (float)scale;
    if (tid == 0){
      dd[k] = (double)A[aoffc(k, k)];
      ee[k] = beta;
      A[aoffc(k, k)] = tau_f;              // stash tau on dead diagonal slot
    }
    if (tau != 0.0){                        // block-uniform branch
      float u_i = 0.f;
      if (rtid < m) u_i = (rtid == 0) ? 1.f : x*scale_f;
      if (team == 0 && rtid < m){
        uu[i] = u_i;
        if (rtid >= 1) A[aoffc(i, k)] = u_i;   // u column for back-transform
      }
      __syncthreads();                                 // B1b: uu ready
      // column geometry
      int c0 = k+1;
      int cA = (c0+3)&~3;
      int cB = (c0+31)&~31;
      int NB = (NN - cB) >> 5;
      const int rb = i*STRD;
      const int rk3 = (3*i) & 7;
      int off[8];
#pragma unroll
      for (int j = 0; j < 8; ++j) off[j] = ((j + rk3) & 7) << 2;
      // matvec partials over this team's columns
      if (rtid < m){
        float s0=0.f, s1=0.f, s2=0.f, s3=0.f, accs=0.f;
        if (team == 3){
          int c = c0;
          for (; c < cA; ++c) accs += A[aoffc(i, c)]*uu[c];
          for (; c < cB; c += 4){
            int c4 = c>>2; int s = (c4&~7)|((c4+rk3)&7);
            float4 a4 = *(const float4*)&A[rb + (s<<2)];
            float4 u4 = *(const float4*)&uu[c];
            s0 += a4.x*u4.x; s1 += a4.y*u4.y; s2 += a4.z*u4.z; s3 += a4.w*u4.w;
          }
        }
        for (int b = team; b < NB; b += 4){
          int c = cB + (b<<5);
          const int cb = rb + c;           // c 32-aligned -> slot-block base == c
#pragma unroll
          for (int j = 0; j < 8; ++j){
            float4 a4 = *(const float4*)&A[cb + off[j]];
            float4 u4 = *(const float4*)&uu[c + 4*j];
            s0 += a4.x*u4.x; s1 += a4.y*u4.y; s2 += a4.z*u4.z; s3 += a4.w*u4.w;
          }
        }
        pp4[team*NN + i] = ((s0+s1)+(s2+s3)) + accs;
      }
      __syncthreads();                                 // B2a: pp4 ready
      float p = 0.f;
      if (rtid < m)
        p = tau_f*(pp4[i] + pp4[NN + i] + pp4[2*NN + i] + pp4[3*NN + i]);
      if (team == 0){
        float vp = (rtid < m) ? u_i*p : 0.f;
        vp = waveSum(vp);
        if (lane == 0) redB[wid] = (double)vp;
      }
      __syncthreads();                                 // B2: vtp ready
      double vtp = redB[0] + redB[1] + redB[2] + redB[3];
      float Kc_f = (float)(0.5*tau*vtp);
      float w_i = 0.f;
      if (rtid < m){
        w_i = p - Kc_f*u_i;
        if (team == 0) ww[i] = w_i;
      }
      __syncthreads();                                 // B2b: ww ready
      if (rtid < m){
        if (team == 3){
          int c = c0;
          for (; c < cA; ++c) A[aoffc(i, c)] -= u_i*ww[c] + w_i*uu[c];
          for (; c < cB; c += 4){
            int c4 = c>>2; int s = (c4&~7)|((c4+rk3)&7);
            float* ap = &A[rb + (s<<2)];
            float4 a4 = *(const float4*)ap;
            float4 u4 = *(const float4*)&uu[c];
            float4 w4 = *(const float4*)&ww[c];
            a4.x -= u_i*w4.x + w_i*u4.x;
            a4.y -= u_i*w4.y + w_i*u4.y;
            a4.z -= u_i*w4.z + w_i*u4.z;
            a4.w -= u_i*w4.w + w_i*u4.w;
            *(float4*)ap = a4;
          }
        }
        for (int b = team; b < NB; b += 4){
          int c = cB + (b<<5);
          const int cb = rb + c;
#pragma unroll
          for (int j = 0; j < 8; ++j){
            float* ap = &A[cb + off[j]];
            float4 a4 = *(const float4*)ap;
            float4 u4 = *(const float4*)&uu[c + 4*j];
            float4 w4 = *(const float4*)&ww[c + 4*j];
            a4.x -= u_i*w4.x + w_i*u4.x;
            a4.y -= u_i*w4.y + w_i*u4.y;
            a4.z -= u_i*w4.z + w_i*u4.z;
            a4.w -= u_i*w4.w + w_i*u4.w;
            *(float4*)ap = a4;
          }
        }
      }
      __syncthreads();                                 // B3: A ready for next k
    } else {
      __syncthreads();                                 // protect redA/salpha reuse
    }
  }

  if (wid != 0) return;                                // wave 0 finishes alone

  // ---- single-wave tail, m <= 64 (k = NN-65..NN-3), barrier-free ----
  for (int k = NN-65; k < NN-2; ++k){
    int m = NN-1-k;
    int i = k+1+lane;
    bool act = lane < m;
    float x = act ? A[aoffc(i, k)] : 0.f;
    float part = (lane > 0) ? x*x : 0.f;
    float sig_f = waveAllSum(part);
    float alpha_f = __shfl(x, 0);
    double sigma = (double)sig_f;
    double alpha = (double)alpha_f;
    double beta, tau, scale;
    if (sigma <= 1e-30){ tau = 0.0; beta = alpha; scale = 0.0; }
    else {
      beta = -copysign(sqrt(alpha*alpha + sigma), alpha);
      tau = (beta - alpha)/beta;
      scale = 1.0/(alpha - beta);
    }
    float tau_f = (float)tau, scale_f = (float)scale;
    if (lane == 0){
      dd[k] = (double)A[aoffc(k, k)];
      ee[k] = beta;
      A[aoffc(k, k)] = tau_f;
    }
    if (tau == 0.0) continue;            // wave-uniform
    float u = (lane == 0) ? 1.f : x*scale_f;   // inactive lanes: x=0 -> u=0
    int base4 = (k+1) & ~3;
    int ph = (k+1) - base4;
    uu[lane + ph] = u;
    if (lane >= 1 && act) A[aoffc(i, k)] = u;
    WAVE_SYNC();
    // matvec p_i = tau * sum_c A[i][c] * u_c
    int ic = act ? i : (k+1);
    const int rb = ic*STRD;
    const int rk3 = (3*ic) & 7;
    float s0=0.f, s1=0.f, s2=0.f, s3=0.f, accs=0.f;
    {
      int c = k+1;
      int cA = (c+3)&~3; if (cA > NN) cA = NN;
      for (; c < cA; ++c) accs += A[aoffc(ic, c)]*uu[c-base4];
      for (; c < NN; c += 4){
        int c4 = c>>2; int s = (c4&~7)|((c4+rk3)&7);
        float4 a4 = *(const float4*)&A[rb + (s<<2)];
        float4 u4 = *(const float4*)&uu[c-base4];
        s0 += a4.x*u4.x; s1 += a4.y*u4.y; s2 += a4.z*u4.z; s3 += a4.w*u4.w;
      }
    }
    float p = tau_f*(((s0+s1)+(s2+s3)) + accs);
    float vtp = waveAllSum(u*p);
    float Kc_f = (float)(0.5*tau*(double)vtp);
    float w = p - Kc_f*u;
    ww[lane + ph] = w;
    WAVE_SYNC();
    if (act){
      int c = k+1;
      int cA = (c+3)&~3; if (cA > NN) cA = NN;
      for (; c < cA; ++c) A[aoffc(i, c)] -= u*ww[c-base4] + w*uu[c-base4];
      for (; c < NN; c += 4){
        int c4 = c>>2; int s = (c4&~7)|((c4+rk3)&7);
        float* ap = &A[rb + (s<<2)];
        float4 a4 = *(const float4*)ap;
        float4 u4 = *(const float4*)&uu[c-base4];
        float4 w4 = *(const float4*)&ww[c-base4];
        a4.x -= u*w4.x + w*u4.x;
        a4.y -= u*w4.y + w*u4.y;
        a4.z -= u*w4.z + w*u4.z;
        a4.w -= u*w4.w + w*u4.w;
        *(float4*)ap = a4;
      }
    }
    WAVE_SYNC();
  }

  if (lane == 0){
    dd[NN-2] = (double)A[aoffc(NN-2, NN-2)];
    ee[NN-2] = (double)A[aoffc(NN-1, NN-2)];
    dd[NN-1] = (double)A[aoffc(NN-1, NN-1)];
  }
  WAVE_SYNC();

  // ---- bisection (wave 0) + serial LU/inverse-iteration (lane 0), fp64 ----
  {
    double mn = 1e300, mx = -1e300;
    for (int i = lane; i < NN; i += 64){
      double r = (i > 0 ? fabs(ee[i-1]) : 0.0) + (i < NN-1 ? fabs(ee[i]) : 0.0);
      mn = fmin(mn, dd[i]-r); mx = fmax(mx, dd[i]+r);
    }
#pragma unroll
    for (int o = 32; o > 0; o >>= 1){
      mn = fmin(mn, __shfl_down(mn, o));
      mx = fmax(mx, __shfl_down(mx, o));
    }
    mn = __shfl(mn, 0); mx = __shfl(mx, 0);
    double lo = mn - 1e-8 - 1e-9*fabs(mn);
    double hi = mx + 1e-8 + 1e-9*fabs(mx);
    for (int it = 0; it < 10; ++it){
      double lam = lo + (hi-lo)*((double)(lane+1)/65.0);
      int cnt = 0;
      double q = dd[0] - lam;
      if (q < 0.0) cnt++;
      for (int i2 = 1; i2 < NN; ++i2){
        double den = q;
        if (fabs(den) < 1e-280) den = (den < 0.0) ? -1e-280 : 1e-280;
        q = dd[i2] - lam - ee[i2-1]*ee[i2-1]/den;
        if (q < 0.0) cnt++;
      }
      unsigned long long bal = __ballot(cnt >= 2);
      if (bal == 0ull){
        lo = lo + (hi-lo)*(64.0/65.0);
      } else {
        int j0 = __ffsll(bal) - 1;
        double nl = lo + (hi-lo)*((double)j0/65.0);
        double nh = lo + (hi-lo)*((double)(j0+1)/65.0);
        lo = nl; hi = nh;
      }
    }
    double lam1 = 0.5*(lo+hi);

    if (lane == 0){
      for (int i = 0; i < NN; ++i) lu_d[i] = dd[i] - lam1;
      for (int i = 0; i < NN-1; ++i){ lu_dl[i] = ee[i]; lu_du[i] = ee[i]; }
      for (int i = 0; i < NN-2; ++i) lu_du2[i] = 0.0;
      for (int i = 0; i < NN-1; ++i){
        if (fabs(lu_d[i]) >= fabs(lu_dl[i])){
          double di = lu_d[i];
          if (fabs(di) < 1e-30){ di = (di < 0.0) ? -1e-30 : 1e-30; lu_d[i] = di; }
          double fact = lu_dl[i]/di;
          lu_dl[i] = fact;
          lu_d[i+1] -= fact*lu_du[i];
          lu_piv[i] = 0;
        } else {
          double fact = lu_d[i]/lu_dl[i];
          lu_d[i] = lu_dl[i];
          double tmp = lu_d[i+1];
          lu_d[i+1] = lu_du[i] - fact*tmp;
          if (i < NN-2){ lu_du2[i] = lu_du[i+1]; lu_du[i+1] = -fact*lu_du[i+1]; }
          lu_du[i] = tmp;
          lu_dl[i] = fact;
          lu_piv[i] = 1;
        }
      }
      if (fabs(lu_d[NN-1]) < 1e-30)
        lu_d[NN-1] = (lu_d[NN-1] < 0.0) ? -1e-30 : 1e-30;
      for (int i = 0; i < NN; ++i) yv[i] = 1.0 + 0.001*(double)((i*37)%29);
      for (int round = 0; round < 2; ++round){
        for (int i = 0; i < NN-1; ++i){
          if (lu_piv[i] == 0){
            yv[i+1] -= lu_dl[i]*yv[i];
          } else {
            double t = yv[i]; yv[i] = yv[i+1]; yv[i+1] = t - lu_dl[i]*yv[i];
          }
        }
        double mx1 = 0.0;
        for (int i = 0; i < NN; ++i) mx1 = fmax(mx1, fabs(yv[i]));
        double inv1 = (mx1 > 0.0 && isfinite(mx1)) ? 1.0/mx1 : 1.0;
        for (int i = 0; i < NN; ++i) yv[i] *= inv1;
        yv[NN-1] = yv[NN-1]/lu_d[NN-1];
        yv[NN-2] = (yv[NN-2] - lu_du[NN-2]*yv[NN-1])/lu_d[NN-2];
        for (int i = NN-3; i >= 0; --i)
          yv[i] = (yv[i] - lu_du[i]*yv[i+1] - lu_du2[i]*yv[i+2])/lu_d[i];
        double mxv = 0.0;
        for (int i = 0; i < NN; ++i) mxv = fmax(mxv, fabs(yv[i]));
        double inv = (mxv > 0.0 && isfinite(mxv)) ? 1.0/mxv : 1.0;
        for (int i = 0; i < NN; ++i){
          double val = yv[i]*inv;
          if (!isfinite(val)) val = 0.0;
          yv[i] = val;
        }
      }
    }
  }
  WAVE_SYNC();

  // ---- back-transform y <- H_0 ... H_{n-3} y  (3 rows/lane in registers) ----
  {
    int r0 = lane, r1 = lane+64, r2 = lane+128;
    double y0 = yv[r0], y1 = yv[r1], y2 = yv[r2];
    for (int k = NN-3; k >= 0; --k){
      double tau = (double)A[aoffc(k, k)];
      if (tau != 0.0){
        double u0 = (r0 > k) ? ((r0 == k+1) ? 1.0 : (double)A[aoffc(r0, k)]) : 0.0;
        double u1 = (r1 > k) ? ((r1 == k+1) ? 1.0 : (double)A[aoffc(r1, k)]) : 0.0;
        double u2 = (r2 > k) ? ((r2 == k+1) ? 1.0 : (double)A[aoffc(r2, k)]) : 0.0;
        double part = u0*y0 + u1*y1 + u2*y2;
        part = waveAllSumD(part);
        double s = tau*part;
        y0 -= s*u0; y1 -= s*u1; y2 -= s*u2;
      }
    }

    const double* dg = darr + (size_t)g*NN;
    double d0 = dg[r0], d1 = dg[r1], d2 = dg[r2];
    double sd0 = sqrt(d0), sd1 = sqrt(d1), sd2 = sqrt(d2);
    double pd  = waveAllSumD(sd0*y0 + sd1*y1 + sd2*y2);
    double pn2 = waveAllSumD(d0 + d1 + d2);
    double coef = pd/fmax(pn2, 1e-300);
    y0 -= coef*sd0; y1 -= coef*sd1; y2 -= coef*sd2;
    double s2 = waveAllSumD(y0*y0 + y1*y1 + y2*y2);
    double nrm = sqrt(s2);
    double inv = (nrm > 0.0 && isfinite(nrm)) ? 1.0/nrm : 0.0;
    double o0 = y0*inv, o1 = y1*inv, o2 = y2*inv;
    if (!isfinite(o0)) o0 = 0.0;
    if (!isfinite(o1)) o1 = 0.0;
    if (!isfinite(o2)) o2 = 0.0;
    v1out[g*NN + r0] = o0;
    v1out[g*NN + r1] = o1;
    v1out[g*NN + r2] = o2;
  }
}

// kmeans on row-normalized [sqrt(d)/||.||, v1]  (fp64)
__global__ __launch_bounds__(256) void k_sg_kmeans(const double* __restrict__ darr,
                                                   const double* __restrict__ v1,
                                                   int* __restrict__ labels){
  __shared__ double px[NN], py[NN], cx[96], cy[96];
  __shared__ int lab[NN];
  __shared__ double red[16];
  int g = blockIdx.x, tid = threadIdx.x;
  double part = 0.0;
  for (int i = tid; i < NN; i += 256) part += darr[g*NN + i];
  double sumd = blockSumD(part, red);
  double invn = 1.0/sqrt(fmax(sumd, 1e-300));
  for (int i = tid; i < NN; i += 256){
    double h0 = sqrt(darr[g*NN + i])*invn;
    double h1 = v1[g*NN + i];
    double rn = sqrt(h0*h0 + h1*h1);
    double ax = h0/rn, ay = h1/rn;
    if (!isfinite(ax)) ax = 0.0;
    if (!isfinite(ay)) ay = 0.0;
    px[i] = ax; py[i] = ay;
  }
  __syncthreads();
  if (tid < 96){ cx[tid] = px[tid]; cy[tid] = py[tid]; }
  __syncthreads();
  for (int it = 0; it <= 10; ++it){
    if (tid < NN){
      double bx = px[tid], by = py[tid];
      double best = 1e300; int bi = 0;
      for (int a = 0; a < 96; ++a){
        double dx = bx - cx[a], dy = by - cy[a];
        double d2 = dx*dx + dy*dy;
        if (d2 < best){ best = d2; bi = a; }
      }
      lab[tid] = bi;
    }
    __syncthreads();
    if (it == 10) break;
    if (tid < 96){
      int c = 0; double sx = 0.0, sy = 0.0;
      for (int i = 0; i < NN; ++i){
        if (lab[i] == tid){ c++; sx += px[i]; sy += py[i]; }
      }
      if (c > 0){ cx[tid] = sx/(double)c; cy[tid] = sy/(double)c; }
      else      { cx[tid] = px[tid];      cy[tid] = py[tid]; }
    }
    __syncthreads();
  }
  if (tid < NN) labels[g*NN + tid] = lab[tid];
}

// S = pos_alpha + neg_alpha (fp64 in, fp32 out)
__global__ void k_sg_alpha(const double* __restrict__ esym, const int* __restrict__ labels,
                           float* __restrict__ S){
  __shared__ int lbs[NN];
  int g = blockIdx.x, j = threadIdx.x;
  if (j < NN) lbs[j] = labels[g*NN + j];
  __syncthreads();
  const double* E = esym + (size_t)g*NN*NN;
  const double NEG = -100000000.0;
  int lj = lbs[j];
  double mp = -1e300, mn = -1e300;
  for (int i = 0; i < NN; ++i){
    double w = E[i*NN + j];
    bool sm = (lbs[i] == lj);
    double vp = sm ? w : w*NEG; vp = vp > 0.0 ? vp : 0.2*vp;
    double vn = sm ? w*NEG : w; vn = vn > 0.0 ? vn : 0.2*vn;
    mp = fmax(mp, vp); mn = fmax(mn, vn);
  }
  double sp = 0.0, sn = 0.0;
  for (int i = 0; i < NN; ++i){
    double w = E[i*NN + j];
    bool sm = (lbs[i] == lj);
    double vp = sm ? w : w*NEG; vp = vp > 0.0 ? vp : 0.2*vp;
    double vn = sm ? w*NEG : w; vn = vn > 0.0 ? vn : 0.2*vn;
    sp += exp(vp - mp); sn += exp(vn - mn);
  }
  float* So = S + (size_t)g*NN*NN;
  for (int i = 0; i < NN; ++i){
    double w = E[i*NN + j];
    bool sm = (lbs[i] == lj);
    double vp = sm ? w : w*NEG; vp = vp > 0.0 ? vp : 0.2*vp;
    double vn = sm ? w*NEG : w; vn = vn > 0.0 ? vn : 0.2*vn;
    So[i*NN + j] = (float)(exp(vp - mp)/sp + exp(vn - mn)/sn);
  }
}

// h_out[i,:] = sum_j S[i,j] * relu(h_in[j,:]) per group
__global__ __launch_bounds__(320) void k_sg_feat(const float* __restrict__ S,
                                                 const float* __restrict__ hin,
                                                 float* __restrict__ hout){
  int r = blockIdx.x;
  int g = r / NN, li = r - g*NN;
  int dh = threadIdx.x;
  const float* Srow = S + (size_t)g*NN*NN + (size_t)li*NN;
  const float* hb = hin + (size_t)g*NN*DH;
  float acc = 0.f;
  for (int j = 0; j < NN; ++j){
    float w = Srow[j];
    float x = hb[(size_t)j*DH + dh];
    acc += w*(x > 0.f ? x : 0.f);
  }
  hout[(size_t)r*DH + dh] = acc;
}

// ---------------- host ----------------

extern "C" void kernel_launch(void* const* d_in, const int* in_sizes, int n_in,
                              void* d_out, int out_size, void* d_ws, size_t ws_size,
                              hipStream_t stream){
  (void)n_in; (void)out_size; (void)ws_size;

  // ---- workspace layout (float offsets) ----
  float* ws = (float*)d_ws;
  float* part  = ws;                       // outproj partials: 20*BB*2 = 61440 f
  float* gates = ws + 98304;               // 1966080 (enc hC alias + graph overlays)
  float* hA    = ws + 2064384;             // 491520
  float* hB    = ws + 2555904;             // 491520
  float* cD    = ws + 3047424;             // 491520
  float* traj  = ws + 3538944;             // 3072
  double* sself_d  = (double*)(ws + 3542016);
  double* sother_d = (double*)(ws + 3545088);
  double* darr_d   = (double*)(ws + 3548160);
  double* v1_d     = (double*)(ws + 3551232);
  int*    labels   = (int*)(ws + 3554304);
  // graph matrices overlay the (dead) gates buffer:
  double* edge_d = (double*)gates;             // 589824 f
  double* esym_d = (double*)(gates + 589824);  // 589824 f
  float*  Afull  = gates + 1179648;            // NG*ATILE = 294912 f
  float*  Smat   = gates;                      // S reuses edge_d space
  float*  hC     = gates;                      // encoder alt h buffer (BB*EHID)
  // fp32 parameter arena:
  float* a_traj = ws + 3555840;            // 61440
  float* a_z    = ws + 3617280;            // 512
  float* a_Wemb = ws + 3617792;            // 128
  float* a_bemb = ws + 3617920;            // 64
  float* a_Wihe = ws + 3617984;            // 65536  (permuted)
  float* a_Whhe = ws + 3683520;            // 262144 (permuted)
  float* a_bihe = ws + 3945664;            // 1024   (permuted bias sum)
  float* a_bhhe = ws + 3946688;            // 1024   (unused)
  float* a_Wihd = ws + 3947712;            // 81920  (permuted)
  float* a_Whhd = ws + 4029632;            // 409600 (permuted)
  float* a_bihd = ws + 4439232;            // 1280   (permuted bias sum)
  float* a_bhhd = ws + 4440512;            // 1280   (unused)
  float* a_Wout = ws + 4441792;            // 640
  float* a_bout = ws + 4442432;            // 64
  float* a_Wne  = ws + 4442496;            // 20480
  float* a_bne  = ws + 4462976;            // 64
  float* a_Watt = ws + 4463040;            // 128
  float* a_batt = ws + 4463168;            // 64
  int* cnt  = (int*)(ws + 4463232);
  int* flag = (int*)(ws + 4463233);
  (void)a_bhhe; (void)a_bhhd;

  const int EIG_LDS = 159248;
  hipFuncSetAttribute((const void*)k_sg_eigen,
                      hipFuncAttributeMaxDynamicSharedMemorySize, EIG_LDS);

  // ---- dtype probe ----
  k_zero_int<<<1, 64, 0, stream>>>(cnt, 2);
  k_probe<<<256, 256, 0, stream>>>((const unsigned short*)d_in[1], in_sizes[1], cnt);
  k_flag<<<1, 1, 0, stream>>>(cnt, flag);

  // ---- convert float inputs to fp32 ----
  CvtArgs ca;
  float* dsts[20] = { a_traj, hB, cD, a_z, a_Wemb, a_bemb, a_Wihe, a_Whhe, a_bihe,
                      a_bhhe, a_Wihd, a_Whhd, a_bihd, a_bhhd, a_Wout, a_bout,
                      a_Wne, a_bne, a_Watt, a_batt };
  for (int i = 0; i < 20; ++i){
    ca.src[i] = d_in[i];
    ca.dst[i] = dsts[i];
    ca.n[i]   = in_sizes[i];
  }
  k_convert<<<dim3(512, 20), 256, 0, stream>>>(ca, flag);

  // ---- interleaved (i,f,g,o)-per-state weight/bias permutes (overwrite slots) ----
  k_permw<<<(4*EHID*64   + 255)/256, 256, 0, stream>>>(d_in[6],  a_Wihe, EHID, 64,   flag);
  k_permw<<<(4*EHID*EHID + 255)/256, 256, 0, stream>>>(d_in[7],  a_Whhe, EHID, EHID, flag);
  k_permb<<<(4*EHID + 255)/256, 256, 0, stream>>>(d_in[8], d_in[9],  a_bihe, EHID, flag);
  k_permw<<<(4*DH*64     + 255)/256, 256, 0, stream>>>(d_in[10], a_Wihd, DH, 64, flag);
  k_permw<<<(4*DH*DH     + 255)/256, 256, 0, stream>>>(d_in[11], a_Whhd, DH, DH, flag);
  k_permb<<<(4*DH + 255)/256, 256, 0, stream>>>(d_in[12], d_in[13], a_bihd, DH, flag);

  // ---- encoder: 8 fused embed+gates+lstm steps, h ping-pong hB<->hC ----
  float* ecur = hB;
  float* eoth = hC;
  for (int t = 0; t < 8; ++t){
    k_gates_lstm<<<dim3(4*EHID/64, BB/64), 256, 0, stream>>>(
        a_traj + (size_t)t*BB*2, a_Wemb, a_bemb,
        a_Wihe, a_Whhe, a_bihe, ecur, eoth, cD, EHID,
        0, 0, part, a_Wout, a_bout, d_out, 0, flag);
    float* tmp = ecur; ecur = eoth; eoth = tmp;
  }
  // ecur == hB after 8 swaps

  // ---- decoder init (fused: concat + zero c + copy traj) ----
  k_decinit<<<(BB*DH+255)/256, 256, 0, stream>>>(ecur, a_z, a_traj + (size_t)7*BB*2,
                                                 hA, cD, traj);

  float* hcur = hA;
  float* hoth = hB;
  for (int i = 0; i < PRED; ++i){
    if (i == 4){
      k_sg_emb<<<BB, 64, 0, stream>>>(hcur, a_Wne, a_bne, a_Watt, sself_d, sother_d);
      k_sg_edgecol<<<NG, NN, 0, stream>>>(sself_d, sother_d, a_batt, edge_d);
      k_sg_symdsum<<<NG*NN, NN, 0, stream>>>(edge_d, esym_d, darr_d);
      k_sg_lsym<<<(NG*NN*NN+255)/256, 256, 0, stream>>>(esym_d, darr_d, Afull);
      k_sg_eigen<<<NG, 1024, EIG_LDS, stream>>>(Afull, darr_d, v1_d);
      k_sg_kmeans<<<NG, 256, 0, stream>>>(darr_d, v1_d, labels);
      k_sg_alpha<<<NG, NN, 0, stream>>>(esym_d, labels, Smat);
      k_sg_feat<<<BB, DH, 0, stream>>>(Smat, hcur, hoth);
      float* tmp = hcur; hcur = hoth; hoth = tmp;
    }
    k_gates_lstm<<<dim3(4*DH/64, BB/64), 256, 0, stream>>>(
        traj, a_Wemb, a_bemb,
        a_Wihd, a_Whhd, a_bihd, hcur, hoth, cD, DH,
        (i > 0) ? 1 : 0, 1, part, a_Wout, a_bout, d_out, i, flag);
    { float* tmp = hcur; hcur = hoth; hoth = tmp; }
  }
  // final output slice (step PRED-1)
  k_finout<<<(BB*2 + 255)/256, 256, 0, stream>>>(part, a_bout, 4*DH/64,
                                                 d_out, PRED-1, flag);
}

// Round 12
// 2239.683 us; speedup vs baseline: 1.0163x; 1.0163x over previous
//
#include <hip/hip_runtime.h>
#include <hip/hip_bf16.h>

typedef __hip_bfloat16 bf16;

#define NN 192      // nodes per group
#define NG 8        // groups
#define BB 1536     // batch
#define EHID 256
#define DH 320      // decoder hidden
#define PRED 12
#define STRD 192    // row stride (floats). Swizzled layout -> no pad needed.
#define ATILE (NN*STRD)   // 36864 floats per group

// Swizzled element offset inside one A tile.
__device__ __forceinline__ int aoffc(int r, int c){
  int c4 = c >> 2;
  int s = (c4 & ~7) | ((c4 + 3*r) & 7);
  return r*STRD + (s << 2) + (c & 3);
}

#define WAVE_SYNC() do { asm volatile("" ::: "memory"); __builtin_amdgcn_wave_barrier(); } while (0)

__device__ __forceinline__ float waveSum(float v){
#pragma unroll
  for (int o = 32; o > 0; o >>= 1) v += __shfl_down(v, o);
  return v;
}
__device__ __forceinline__ double waveSumD(double v){
#pragma unroll
  for (int o = 32; o > 0; o >>= 1) v += __shfl_down(v, o);
  return v;
}
__device__ __forceinline__ float waveAllSum(float v){
#pragma unroll
  for (int o = 32; o > 0; o >>= 1) v += __shfl_xor(v, o);
  return v;
}
__device__ __forceinline__ double waveAllSumD(double v){
#pragma unroll
  for (int o = 32; o > 0; o >>= 1) v += __shfl_xor(v, o);
  return v;
}

__device__ __forceinline__ double blockSumD(double v, double* red){
  int lane = threadIdx.x & 63, wid = threadIdx.x >> 6, nw = (int)blockDim.x >> 6;
  double s = waveSumD(v);
  __syncthreads();
  if (lane == 0) red[wid] = s;
  __syncthreads();
  if (wid == 0){
    double t = (lane < nw) ? red[lane] : 0.0;
    t = waveSumD(t);
    if (lane == 0) red[0] = t;
  }
  __syncthreads();
  return red[0];
}

// ---------------- dtype probe + conversion ----------------

__global__ void k_zero_int(int* __restrict__ p, int n){
  int i = blockIdx.x*blockDim.x + threadIdx.x;
  if (i < n) p[i] = 0;
}

__global__ void k_probe(const unsigned short* __restrict__ src, int n, int* __restrict__ cnt){
  int tid = blockIdx.x*blockDim.x + threadIdx.x;
  int stride = gridDim.x*blockDim.x;
  int bad = 0;
  for (int j = tid; j < n; j += stride){
    float v = __uint_as_float(((unsigned int)src[j]) << 16);
    if (!(fabsf(v) < 100.f)) bad++;
  }
#pragma unroll
  for (int o = 32; o > 0; o >>= 1) bad += __shfl_down(bad, o);
  if ((threadIdx.x & 63) == 0 && bad > 0) atomicAdd(cnt, bad);
}
__global__ void k_flag(const int* __restrict__ cnt, int* __restrict__ flag){
  *flag = (*cnt > 4096) ? 1 : 0;        // 1 = inputs are fp32, 0 = bf16
}

struct CvtArgs {
  const void* src[20];
  float*      dst[20];
  int         n[20];
};

__global__ void k_convert(CvtArgs a, const int* __restrict__ flag){
  int id = blockIdx.y;
  int n = a.n[id];
  float* d = a.dst[id];
  int t = blockIdx.x*blockDim.x + threadIdx.x;
  int stride = gridDim.x*blockDim.x;
  if (*flag == 0){
    const bf16* s = (const bf16*)a.src[id];
    for (int j = t; j < n; j += stride) d[j] = __bfloat162float(s[j]);
  } else {
    const float* s = (const float*)a.src[id];
    for (int j = t; j < n; j += stride) d[j] = s[j];
  }
}

// permuted weight convert: dst[(4*j+q)*K + kk] = src[(q*H+j)*K + kk]
__global__ void k_permw(const void* __restrict__ src, float* __restrict__ dst,
                        int H, int K, const int* __restrict__ flag){
  int idx = blockIdx.x*blockDim.x + threadIdx.x;
  int n = 4*H*K;
  if (idx >= n) return;
  int r = idx / K, kk = idx - r*K;
  int j = r >> 2, q = r & 3;
  int si = (q*H + j)*K + kk;
  float v;
  if (*flag == 0) v = __bfloat162float(((const bf16*)src)[si]);
  else            v = ((const float*)src)[si];
  dst[idx] = v;
}

// permuted bias sum: dst[4j+q] = b1[q*H+j] + b2[q*H+j]
__global__ void k_permb(const void* __restrict__ b1, const void* __restrict__ b2,
                        float* __restrict__ dst, int H, const int* __restrict__ flag){
  int r = blockIdx.x*blockDim.x + threadIdx.x;
  if (r >= 4*H) return;
  int j = r >> 2, q = r & 3;
  int si = q*H + j;
  float v1, v2;
  if (*flag == 0){
    v1 = __bfloat162float(((const bf16*)b1)[si]);
    v2 = __bfloat162float(((const bf16*)b2)[si]);
  } else {
    v1 = ((const float*)b1)[si];
    v2 = ((const float*)b2)[si];
  }
  dst[r] = v1 + v2;
}

// ---------------- small kernels ----------------

// fused decoder init: h = [henc | z], c = 0, traj = t7  (3 launches -> 1)
__global__ void k_decinit(const float* __restrict__ henc, const float* __restrict__ z,
                          const float* __restrict__ t7, float* __restrict__ h,
                          float* __restrict__ c, float* __restrict__ traj){
  int idx = blockIdx.x*blockDim.x + threadIdx.x;
  if (idx < BB*2) traj[idx] = t7[idx];
  if (idx >= BB*DH) return;
  int b = idx / DH, j = idx - b*DH;
  h[idx] = (j < EHID) ? henc[b*EHID + j] : z[(b/NN)*64 + (j - EHID)];
  c[idx] = 0.f;
}

// FUSED embed + gates-GEMM + LSTM pointwise.
// Weights Wp [4H][64], Up [4H][H] are interleaved: row 4j+q = gate q of state j.
// Each 64-wide column tile = 16 complete states -> LSTM applied in epilogue.
__global__ __launch_bounds__(256) void k_gates_lstm(
    const float* __restrict__ traj2,   // [BB][2] input positions
    const float* __restrict__ Wemb, const float* __restrict__ bemb,
    const float* __restrict__ Wp, const float* __restrict__ Up,
    const float* __restrict__ bsum,
    const float* __restrict__ hin, float* __restrict__ hout,
    float* __restrict__ cst, int H){
  __shared__ __align__(16) float inpT[64][68];   // embed tile, [k][row]
  __shared__ __align__(16) float As[32][68];
  __shared__ __align__(16) float Ws[32][68];
  int tid = threadIdx.x;
  int tx = tid & 15, ty = tid >> 4;
  int n0 = blockIdx.x * 64, m0 = blockIdx.y * 64;

  // embed tile: inpT[e][r] = relu(Wemb[e]·xy_r + bemb[e])
  {
    int r = tid & 63;
    float x = traj2[(size_t)(m0 + r)*2];
    float y = traj2[(size_t)(m0 + r)*2 + 1];
    for (int e = tid >> 6; e < 64; e += 4){
      float v = Wemb[e*2]*x + Wemb[e*2+1]*y + bemb[e];
      inpT[e][r] = v > 0.f ? v : 0.f;
    }
  }
  float acc[4][4] = {};
  // phase 0: K=64 (embed) from inpT
  for (int k0 = 0; k0 < 64; k0 += 32){
    {
      int am = tid >> 2, ak = (tid & 3) * 8;
      const float* srcW = Wp + (size_t)(n0+am)*64 + k0 + ak;
      float4 w0 = *(const float4*)(srcW);
      float4 w1 = *(const float4*)(srcW+4);
      Ws[ak+0][am]=w0.x; Ws[ak+1][am]=w0.y; Ws[ak+2][am]=w0.z; Ws[ak+3][am]=w0.w;
      Ws[ak+4][am]=w1.x; Ws[ak+5][am]=w1.y; Ws[ak+6][am]=w1.z; Ws[ak+7][am]=w1.w;
    }
    __syncthreads();
#pragma unroll
    for (int k = 0; k < 32; ++k){
      float4 a0 = *(const float4*)&inpT[k0+k][ty*4];
      float4 b0 = *(const float4*)&Ws[k][tx*4];
      float av[4] = {a0.x, a0.y, a0.z, a0.w};
      float bv[4] = {b0.x, b0.y, b0.z, b0.w};
#pragma unroll
      for (int i = 0; i < 4; ++i)
#pragma unroll
        for (int j = 0; j < 4; ++j)
          acc[i][j] += av[i]*bv[j];
    }
    __syncthreads();
  }
  // phase 1: K=H (recurrent)
  for (int k0 = 0; k0 < H; k0 += 32){
    {
      int am = tid >> 2, ak = (tid & 3) * 8;
      const float* srcA = hin + (size_t)(m0+am)*H + k0 + ak;
      float4 f0 = *(const float4*)(srcA);
      float4 f1 = *(const float4*)(srcA+4);
      As[ak+0][am]=f0.x; As[ak+1][am]=f0.y; As[ak+2][am]=f0.z; As[ak+3][am]=f0.w;
      As[ak+4][am]=f1.x; As[ak+5][am]=f1.y; As[ak+6][am]=f1.z; As[ak+7][am]=f1.w;
      const float* srcW = Up + (size_t)(n0+am)*H + k0 + ak;
      float4 w0 = *(const float4*)(srcW);
      float4 w1 = *(const float4*)(srcW+4);
      Ws[ak+0][am]=w0.x; Ws[ak+1][am]=w0.y; Ws[ak+2][am]=w0.z; Ws[ak+3][am]=w0.w;
      Ws[ak+4][am]=w1.x; Ws[ak+5][am]=w1.y; Ws[ak+6][am]=w1.z; Ws[ak+7][am]=w1.w;
    }
    __syncthreads();
#pragma unroll
    for (int k = 0; k < 32; ++k){
      float4 a0 = *(const float4*)&As[k][ty*4];
      float4 b0 = *(const float4*)&Ws[k][tx*4];
      float av[4] = {a0.x, a0.y, a0.z, a0.w};
      float bv[4] = {b0.x, b0.y, b0.z, b0.w};
#pragma unroll
      for (int i = 0; i < 4; ++i)
#pragma unroll
        for (int j = 0; j < 4; ++j)
          acc[i][j] += av[i]*bv[j];
    }
    __syncthreads();
  }
  // epilogue: cols n0+tx*4+{0..3} = (i,f,g,o) of state s
  int s = (n0 >> 2) + tx;
  float4 bq = *(const float4*)&bsum[n0 + tx*4];
#pragma unroll
  for (int i2 = 0; i2 < 4; ++i2){
    int row = m0 + ty*4 + i2;
    float gi = acc[i2][0] + bq.x;
    float gf = acc[i2][1] + bq.y;
    float gg = acc[i2][2] + bq.z;
    float go = acc[i2][3] + bq.w;
    float si = 1.f/(1.f+expf(-gi));
    float sf = 1.f/(1.f+expf(-gf));
    float so = 1.f/(1.f+expf(-go));
    size_t cidx = (size_t)row*H + s;
    float cc = sf*cst[cidx] + si*tanhf(gg);
    cst[cidx] = cc;
    hout[cidx] = so*tanhf(cc);
  }
}

// h(1536x320) -> traj(1536x2) fp32 + output slice `step` (fp32 or bf16 per flag)
__global__ void k_outproj(const float* __restrict__ h, const float* __restrict__ W,
                          const float* __restrict__ bo, float* __restrict__ traj,
                          void* __restrict__ outbase, int step, const int* __restrict__ flag){
  int b = blockIdx.x, lane = threadIdx.x;
  const float* hb = h + (size_t)b*DH;
  float a0 = 0.f, a1 = 0.f;
  for (int k = lane; k < DH; k += 64){
    float hv = hb[k];
    a0 += hv*W[k];
    a1 += hv*W[DH+k];
  }
  a0 = waveSum(a0); a1 = waveSum(a1);
  if (lane == 0){
    a0 += bo[0]; a1 += bo[1];
    traj[b*2] = a0; traj[b*2+1] = a1;
    size_t idx = (size_t)step*BB*2 + (size_t)b*2;
    if (*flag == 0){
      bf16* o = (bf16*)outbase;
      o[idx] = __float2bfloat16(a0); o[idx+1] = __float2bfloat16(a1);
    } else {
      float* o = (float*)outbase;
      o[idx] = a0; o[idx+1] = a1;
    }
  }
}

// ---------------- signed-graph kernels ----------------

__global__ void k_sg_emb(const float* __restrict__ h, const float* __restrict__ Wne,
                         const float* __restrict__ bne, const float* __restrict__ Watt,
                         double* __restrict__ sself, double* __restrict__ sother){
  int node = blockIdx.x, e = threadIdx.x;
  const float* hb = h + (size_t)node*DH;
  double acc = (double)bne[e];
  for (int k = 0; k < DH; ++k) acc += (double)hb[k]*(double)Wne[e*DH+k];
  double po = acc * (double)Watt[e];
  double ps = acc * (double)Watt[64+e];
  po = waveSumD(po); ps = waveSumD(ps);
  if (e == 0){ sother[node] = po; sself[node] = ps; }
}

__global__ void k_sg_edgecol(const double* __restrict__ sself, const double* __restrict__ sother,
                             const float* __restrict__ batt, double* __restrict__ edge){
  int g = blockIdx.x, j = threadIdx.x;
  const double* ss = sself + g*NN;
  double bb = (double)batt[0];
  double sj = sother[g*NN + j];
  double m = -1e300;
  for (int i = 0; i < NN; ++i){
    double e = ss[i] + sj + bb; e = e > 0.0 ? e : 0.2*e;
    m = fmax(m, e);
  }
  double sum = 0.0;
  for (int i = 0; i < NN; ++i){
    double e = ss[i] + sj + bb; e = e > 0.0 ? e : 0.2*e;
    sum += exp(e - m);
  }
  double* E = edge + (size_t)g*NN*NN;
  for (int i = 0; i < NN; ++i){
    double e = ss[i] + sj + bb; e = e > 0.0 ? e : 0.2*e;
    E[i*NN + j] = exp(e - m)/sum;
  }
}

// fused: esym row build + row-sum (sym + dsum in one pass). block = (g,i) row.
__global__ void k_sg_symdsum(const double* __restrict__ edge, double* __restrict__ esym,
                             double* __restrict__ darr){
  int gi = blockIdx.x;                 // 0..NG*NN-1
  int g = gi / NN, i = gi - g*NN;
  int j = threadIdx.x;                 // 192 threads = 3 waves
  __shared__ double red[4];
  const double* E = edge + (size_t)g*NN*NN;
  double w = (i <= j) ? E[(size_t)i*NN + j] : E[(size_t)j*NN + i];
  esym[(size_t)g*NN*NN + (size_t)i*NN + j] = w;
  double sres = waveSumD(w);
  int lane = j & 63, w2 = j >> 6;
  if (lane == 0) red[w2] = sres;
  __syncthreads();
  if (j == 0) darr[gi] = fmax(red[0] + red[1] + red[2], 1e-300);
}

__global__ void k_sg_lsym(const double* __restrict__ esym, const double* __restrict__ darr,
                          float* __restrict__ Afull){
  int idx = blockIdx.x*blockDim.x + threadIdx.x;
  if (idx >= NG*NN*NN) return;
  int g = idx / (NN*NN), r = idx - g*NN*NN;
  int i = r / NN, j = r - i*NN;
  double w = esym[idx];
  double lij = (i == j) ? (darr[g*NN+i] - w) : (-w);
  Afull[(size_t)g*ATILE + aoffc(i, j)] =
      (float)(lij / (sqrt(darr[g*NN+i])*sqrt(darr[g*NN+j])));
}

// LDS-resident swizzled fp32 Householder tridiag, TLP version (round-4 verbatim,
// best measured: 1034-1038 us):
//  * 1024 threads = 4 column-teams x 256 row-threads (16 waves, 4/SIMD)
//  * matvec: per-team partials into pp4[team*NN+i] (stride-1, conflict-free)
//  * rank-2: each team updates its column blocks
//  * 6 barriers / iteration; barrier-free single-wave tail for m <= 64
//  * fp64 Sturm bisection + serial LU inverse iteration (wave 0)
//  * register back-transform + Gram-Schmidt on wave 0 (3 rows/lane)
// dynamic LDS = 159248 B.
__global__ __launch_bounds__(1024) void k_sg_eigen(const float* __restrict__ Afull,
                                                   const double* __restrict__ darr,
                                                   double* __restrict__ v1out){
  extern __shared__ unsigned char ldsraw[];
  float*  A     = (float*)ldsraw;                       // ATILE fp32 (147456 B)
  double* dd    = (double*)(ldsraw + 147456);           // NN
  double* ee    = dd + NN;                              // NN
  double* yv    = ee + NN;                              // NN (block-phase: aliased by pp4)
  double* lu_d  = yv + NN;                              // NN (block-phase: aliased by pp4)
  double* lu_du = lu_d + NN;                            // NN
  double* lu_du2= lu_du + NN;                           // NN   (ends 156672 B)
  double* redA  = lu_du2 + NN;                          // 16   (-> 156800 B)
  double* redB  = redA + 16;                            // 16   (-> 156928 B)
  double* salpha= redB + 16;                            // 1    (-> 156936 B)
  float*  uu    = (float*)(ldsraw + 156944);            // NN fp32 (-> 157712 B)
  float*  ww    = uu + NN;                              // NN fp32 (-> 158480 B)
  int*    lu_piv= (int*)(ww + NN);                      // NN int  (-> 159248 B)
  float*  pp4   = (float*)yv;                           // alias: 4*NN fp32 over yv+lu_d
  double* lu_dl = (double*)uu;                          // alias (uu+ww dead in LU)

  int g = blockIdx.x, tid = threadIdx.x;
  int lane = tid & 63, wid = tid >> 6;   // 16 waves
  int rtid = tid & 255, team = tid >> 8; // 4 teams x 256 row-threads

  const float* src = Afull + (size_t)g*ATILE;
  for (int t = tid*4; t < ATILE; t += 4096) *(float4*)&A[t] = *(const float4*)&src[t];
  __syncthreads();

  // ---- block-wide Householder, m > 64 (k = 0..NN-66) ----
  for (int k = 0; k < NN-65; ++k){
    int m = NN-1-k;
    int i = k+1+rtid;
    float x = 0.f;
    if (rtid < m) x = A[aoffc(i, k)];    // all teams read (same col -> broadcast)
    if (tid == 0) *salpha = (double)x;
    if (team == 0){
      float part = (rtid > 0 && rtid < m) ? x*x : 0.f;
      part = waveSum(part);
      if (lane == 0) redA[wid] = (double)part;   // wid 0..3
    }
    __syncthreads();                                   // B1: sigma + alpha ready
    double sigma = redA[0] + redA[1] + redA[2] + redA[3];
    double alpha = *salpha;
    double beta, tau, scale;
    if (sigma <= 1e-30){ tau = 0.0; beta = alpha; scale = 0.0; }
    else {
      beta = -copysign(sqrt(alpha*alpha + sigma), alpha);
      tau = (beta - alpha)/beta;
      scale = 1.0/(alpha - beta);
    }
    float tau_f = (float)tau, scale_f = (float)scale;
    if (tid == 0){
      dd[k] = (double)A[aoffc(k, k)];
      ee[k] = beta;
      A[aoffc(k, k)] = tau_f;              // stash tau on dead diagonal slot
    }
    if (tau != 0.0){                        // block-uniform branch
      float u_i = 0.f;
      if (rtid < m) u_i = (rtid == 0) ? 1.f : x*scale_f;
      if (team == 0 && rtid < m){
        uu[i] = u_i;
        if (rtid >= 1) A[aoffc(i, k)] = u_i;   // u column for back-transform
      }
      __syncthreads();                                 // B1b: uu ready
      // column geometry
      int c0 = k+1;
      int cA = (c0+3)&~3;
      int cB = (c0+31)&~31;
      int NB = (NN - cB) >> 5;
      const int rb = i*STRD;
      const int rk3 = (3*i) & 7;
      int off[8];
#pragma unroll
      for (int j = 0; j < 8; ++j) off[j] = ((j + rk3) & 7) << 2;
      // matvec partials over this team's columns
      if (rtid < m){
        float s0=0.f, s1=0.f, s2=0.f, s3=0.f, accs=0.f;
        if (team == 3){
          int c = c0;
          for (; c < cA; ++c) accs += A[aoffc(i, c)]*uu[c];
          for (; c < cB; c += 4){
            int c4 = c>>2; int s = (c4&~7)|((c4+rk3)&7);
            float4 a4 = *(const float4*)&A[rb + (s<<2)];
            float4 u4 = *(const float4*)&uu[c];
            s0 += a4.x*u4.x; s1 += a4.y*u4.y; s2 += a4.z*u4.z; s3 += a4.w*u4.w;
          }
        }
        for (int b = team; b < NB; b += 4){
          int c = cB + (b<<5);
          const int cb = rb + c;           // c 32-aligned -> slot-block base == c
#pragma unroll
          for (int j = 0; j < 8; ++j){
            float4 a4 = *(const float4*)&A[cb + off[j]];
            float4 u4 = *(const float4*)&uu[c + 4*j];
            s0 += a4.x*u4.x; s1 += a4.y*u4.y; s2 += a4.z*u4.z; s3 += a4.w*u4.w;
          }
        }
        pp4[team*NN + i] = ((s0+s1)+(s2+s3)) + accs;
      }
      __syncthreads();                                 // B2a: pp4 ready
      float p = 0.f;
      if (rtid < m)
        p = tau_f*(pp4[i] + pp4[NN + i] + pp4[2*NN + i] + pp4[3*NN + i]);
      if (team == 0){
        float vp = (rtid < m) ? u_i*p : 0.f;
        vp = waveSum(vp);
        if (lane == 0) redB[wid] = (double)vp;
      }
      __syncthreads();                                 // B2: vtp ready
      double vtp = redB[0] + redB[1] + redB[2] + redB[3];
      float Kc_f = (float)(0.5*tau*vtp);
      float w_i = 0.f;
      if (rtid < m){
        w_i = p - Kc_f*u_i;
        if (team == 0) ww[i] = w_i;
      }
      __syncthreads();                                 // B2b: ww ready
      if (rtid < m){
        if (team == 3){
          int c = c0;
          for (; c < cA; ++c) A[aoffc(i, c)] -= u_i*ww[c] + w_i*uu[c];
          for (; c < cB; c += 4){
            int c4 = c>>2; int s = (c4&~7)|((c4+rk3)&7);
            float* ap = &A[rb + (s<<2)];
            float4 a4 = *(const float4*)ap;
            float4 u4 = *(const float4*)&uu[c];
            float4 w4 = *(const float4*)&ww[c];
            a4.x -= u_i*w4.x + w_i*u4.x;
            a4.y -= u_i*w4.y + w_i*u4.y;
            a4.z -= u_i*w4.z + w_i*u4.z;
            a4.w -= u_i*w4.w + w_i*u4.w;
            *(float4*)ap = a4;
          }
        }
        for (int b = team; b < NB; b += 4){
          int c = cB + (b<<5);
          const int cb = rb + c;
#pragma unroll
          for (int j = 0; j < 8; ++j){
            float* ap = &A[cb + off[j]];
            float4 a4 = *(const float4*)ap;
            float4 u4 = *(const float4*)&uu[c + 4*j];
            float4 w4 = *(const float4*)&ww[c + 4*j];
            a4.x -= u_i*w4.x + w_i*u4.x;
            a4.y -= u_i*w4.y + w_i*u4.y;
            a4.z -= u_i*w4.z + w_i*u4.z;
            a4.w -= u_i*w4.w + w_i*u4.w;
            *(float4*)ap = a4;
          }
        }
      }
      __syncthreads();                                 // B3: A ready for next k
    } else {
      __syncthreads();                                 // protect redA/salpha reuse
    }
  }

  if (wid != 0) return;                                // wave 0 finishes alone

  // ---- single-wave tail, m <= 64 (k = NN-65..NN-3), barrier-free ----
  for (int k = NN-65; k < NN-2; ++k){
    int m = NN-1-k;
    int i = k+1+lane;
    bool act = lane < m;
    float x = act ? A[aoffc(i, k)] : 0.f;
    float part = (lane > 0) ? x*x : 0.f;
    float sig_f = waveAllSum(part);
    float alpha_f = __shfl(x, 0);
    double sigma = (double)sig_f;
    double alpha = (double)alpha_f;
    double beta, tau, scale;
    if (sigma <= 1e-30){ tau = 0.0; beta = alpha; scale = 0.0; }
    else {
      beta = -copysign(sqrt(alpha*alpha + sigma), alpha);
      tau = (beta - alpha)/beta;
      scale = 1.0/(alpha - beta);
    }
    float tau_f = (float)tau, scale_f = (float)scale;
    if (lane == 0){
      dd[k] = (double)A[aoffc(k, k)];
      ee[k] = beta;
      A[aoffc(k, k)] = tau_f;
    }
    if (tau == 0.0) continue;            // wave-uniform
    float u = (lane == 0) ? 1.f : x*scale_f;   // inactive lanes: x=0 -> u=0
    int base4 = (k+1) & ~3;
    int ph = (k+1) - base4;
    uu[lane + ph] = u;
    if (lane >= 1 && act) A[aoffc(i, k)] = u;
    WAVE_SYNC();
    // matvec p_i = tau * sum_c A[i][c] * u_c
    int ic = act ? i : (k+1);
    const int rb = ic*STRD;
    const int rk3 = (3*ic) & 7;
    float s0=0.f, s1=0.f, s2=0.f, s3=0.f, accs=0.f;
    {
      int c = k+1;
      int cA = (c+3)&~3; if (cA > NN) cA = NN;
      for (; c < cA; ++c) accs += A[aoffc(ic, c)]*uu[c-base4];
      for (; c < NN; c += 4){
        int c4 = c>>2; int s = (c4&~7)|((c4+rk3)&7);
        float4 a4 = *(const float4*)&A[rb + (s<<2)];
        float4 u4 = *(const float4*)&uu[c-base4];
        s0 += a4.x*u4.x; s1 += a4.y*u4.y; s2 += a4.z*u4.z; s3 += a4.w*u4.w;
      }
    }
    float p = tau_f*(((s0+s1)+(s2+s3)) + accs);
    float vtp = waveAllSum(u*p);
    float Kc_f = (float)(0.5*tau*(double)vtp);
    float w = p - Kc_f*u;
    ww[lane + ph] = w;
    WAVE_SYNC();
    if (act){
      int c = k+1;
      int cA = (c+3)&~3; if (cA > NN) cA = NN;
      for (; c < cA; ++c) A[aoffc(i, c)] -= u*ww[c-base4] + w*uu[c-base4];
      for (; c < NN; c += 4){
        int c4 = c>>2; int s = (c4&~7)|((c4+rk3)&7);
        float* ap = &A[rb + (s<<2)];
        float4 a4 = *(const float4*)ap;
        float4 u4 = *(const float4*)&uu[c-base4];
        float4 w4 = *(const float4*)&ww[c-base4];
        a4.x -= u*w4.x + w*u4.x;
        a4.y -= u*w4.y + w*u4.y;
        a4.z -= u*w4.z + w*u4.z;
        a4.w -= u*w4.w + w*u4.w;
        *(float4*)ap = a4;
      }
    }
    WAVE_SYNC();
  }

  if (lane == 0){
    dd[NN-2] = (double)A[aoffc(NN-2, NN-2)];
    ee[NN-2] = (double)A[aoffc(NN-1, NN-2)];
    dd[NN-1] = (double)A[aoffc(NN-1, NN-1)];
  }
  WAVE_SYNC();

  // ---- bisection (wave 0) + serial LU/inverse-iteration (lane 0), fp64 ----
  {
    double mn = 1e300, mx = -1e300;
    for (int i = lane; i < NN; i += 64){
      double r = (i > 0 ? fabs(ee[i-1]) : 0.0) + (i < NN-1 ? fabs(ee[i]) : 0.0);
      mn = fmin(mn, dd[i]-r); mx = fmax(mx, dd[i]+r);
    }
#pragma unroll
    for (int o = 32; o > 0; o >>= 1){
      mn = fmin(mn, __shfl_down(mn, o));
      mx = fmax(mx, __shfl_down(mx, o));
    }
    mn = __shfl(mn, 0); mx = __shfl(mx, 0);
    double lo = mn - 1e-8 - 1e-9*fabs(mn);
    double hi = mx + 1e-8 + 1e-9*fabs(mx);
    for (int it = 0; it < 10; ++it){
      double lam = lo + (hi-lo)*((double)(lane+1)/65.0);
      int cnt = 0;
      double q = dd[0] - lam;
      if (q < 0.0) cnt++;
      for (int i2 = 1; i2 < NN; ++i2){
        double den = q;
        if (fabs(den) < 1e-280) den = (den < 0.0) ? -1e-280 : 1e-280;
        q = dd[i2] - lam - ee[i2-1]*ee[i2-1]/den;
        if (q < 0.0) cnt++;
      }
      unsigned long long bal = __ballot(cnt >= 2);
      if (bal == 0ull){
        lo = lo + (hi-lo)*(64.0/65.0);
      } else {
        int j0 = __ffsll(bal) - 1;
        double nl = lo + (hi-lo)*((double)j0/65.0);
        double nh = lo + (hi-lo)*((double)(j0+1)/65.0);
        lo = nl; hi = nh;
      }
    }
    double lam1 = 0.5*(lo+hi);

    if (lane == 0){
      for (int i = 0; i < NN; ++i) lu_d[i] = dd[i] - lam1;
      for (int i = 0; i < NN-1; ++i){ lu_dl[i] = ee[i]; lu_du[i] = ee[i]; }
      for (int i = 0; i < NN-2; ++i) lu_du2[i] = 0.0;
      for (int i = 0; i < NN-1; ++i){
        if (fabs(lu_d[i]) >= fabs(lu_dl[i])){
          double di = lu_d[i];
          if (fabs(di) < 1e-30){ di = (di < 0.0) ? -1e-30 : 1e-30; lu_d[i] = di; }
          double fact = lu_dl[i]/di;
          lu_dl[i] = fact;
          lu_d[i+1] -= fact*lu_du[i];
          lu_piv[i] = 0;
        } else {
          double fact = lu_d[i]/lu_dl[i];
          lu_d[i] = lu_dl[i];
          double tmp = lu_d[i+1];
          lu_d[i+1] = lu_du[i] - fact*tmp;
          if (i < NN-2){ lu_du2[i] = lu_du[i+1]; lu_du[i+1] = -fact*lu_du[i+1]; }
          lu_du[i] = tmp;
          lu_dl[i] = fact;
          lu_piv[i] = 1;
        }
      }
      if (fabs(lu_d[NN-1]) < 1e-30)
        lu_d[NN-1] = (lu_d[NN-1] < 0.0) ? -1e-30 : 1e-30;
      for (int i = 0; i < NN; ++i) yv[i] = 1.0 + 0.001*(double)((i*37)%29);
      for (int round = 0; round < 2; ++round){
        for (int i = 0; i < NN-1; ++i){
          if (lu_piv[i] == 0){
            yv[i+1] -= lu_dl[i]*yv[i];
          } else {
            double t = yv[i]; yv[i] = yv[i+1]; yv[i+1] = t - lu_dl[i]*yv[i];
          }
        }
        double mx1 = 0.0;
        for (int i = 0; i < NN; ++i) mx1 = fmax(mx1, fabs(yv[i]));
        double inv1 = (mx1 > 0.0 && isfinite(mx1)) ? 1.0/mx1 : 1.0;
        for (int i = 0; i < NN; ++i) yv[i] *= inv1;
        yv[NN-1] = yv[NN-1]/lu_d[NN-1];
        yv[NN-2] = (yv[NN-2] - lu_du[NN-2]*yv[NN-1])/lu_d[NN-2];
        for (int i = NN-3; i >= 0; --i)
          yv[i] = (yv[i] - lu_du[i]*yv[i+1] - lu_du2[i]*yv[i+2])/lu_d[i];
        double mxv = 0.0;
        for (int i = 0; i < NN; ++i) mxv = fmax(mxv, fabs(yv[i]));
        double inv = (mxv > 0.0 && isfinite(mxv)) ? 1.0/mxv : 1.0;
        for (int i = 0; i < NN; ++i){
          double val = yv[i]*inv;
          if (!isfinite(val)) val = 0.0;
          yv[i] = val;
        }
      }
    }
  }
  WAVE_SYNC();

  // ---- back-transform y <- H_0 ... H_{n-3} y  (3 rows/lane in registers) ----
  {
    int r0 = lane, r1 = lane+64, r2 = lane+128;
    double y0 = yv[r0], y1 = yv[r1], y2 = yv[r2];
    for (int k = NN-3; k >= 0; --k){
      double tau = (double)A[aoffc(k, k)];
      if (tau != 0.0){
        double u0 = (r0 > k) ? ((r0 == k+1) ? 1.0 : (double)A[aoffc(r0, k)]) : 0.0;
        double u1 = (r1 > k) ? ((r1 == k+1) ? 1.0 : (double)A[aoffc(r1, k)]) : 0.0;
        double u2 = (r2 > k) ? ((r2 == k+1) ? 1.0 : (double)A[aoffc(r2, k)]) : 0.0;
        double part = u0*y0 + u1*y1 + u2*y2;
        part = waveAllSumD(part);
        double s = tau*part;
        y0 -= s*u0; y1 -= s*u1; y2 -= s*u2;
      }
    }

    const double* dg = darr + (size_t)g*NN;
    double d0 = dg[r0], d1 = dg[r1], d2 = dg[r2];
    double sd0 = sqrt(d0), sd1 = sqrt(d1), sd2 = sqrt(d2);
    double pd  = waveAllSumD(sd0*y0 + sd1*y1 + sd2*y2);
    double pn2 = waveAllSumD(d0 + d1 + d2);
    double coef = pd/fmax(pn2, 1e-300);
    y0 -= coef*sd0; y1 -= coef*sd1; y2 -= coef*sd2;
    double s2 = waveAllSumD(y0*y0 + y1*y1 + y2*y2);
    double nrm = sqrt(s2);
    double inv = (nrm > 0.0 && isfinite(nrm)) ? 1.0/nrm : 0.0;
    double o0 = y0*inv, o1 = y1*inv, o2 = y2*inv;
    if (!isfinite(o0)) o0 = 0.0;
    if (!isfinite(o1)) o1 = 0.0;
    if (!isfinite(o2)) o2 = 0.0;
    v1out[g*NN + r0] = o0;
    v1out[g*NN + r1] = o1;
    v1out[g*NN + r2] = o2;
  }
}

// kmeans on row-normalized [sqrt(d)/||.||, v1]  (fp64)
__global__ __launch_bounds__(256) void k_sg_kmeans(const double* __restrict__ darr,
                                                   const double* __restrict__ v1,
                                                   int* __restrict__ labels){
  __shared__ double px[NN], py[NN], cx[96], cy[96];
  __shared__ int lab[NN];
  __shared__ double red[16];
  int g = blockIdx.x, tid = threadIdx.x;
  double part = 0.0;
  for (int i = tid; i < NN; i += 256) part += darr[g*NN + i];
  double sumd = blockSumD(part, red);
  double invn = 1.0/sqrt(fmax(sumd, 1e-300));
  for (int i = tid; i < NN; i += 256){
    double h0 = sqrt(darr[g*NN + i])*invn;
    double h1 = v1[g*NN + i];
    double rn = sqrt(h0*h0 + h1*h1);
    double ax = h0/rn, ay = h1/rn;
    if (!isfinite(ax)) ax = 0.0;
    if (!isfinite(ay)) ay = 0.0;
    px[i] = ax; py[i] = ay;
  }
  __syncthreads();
  if (tid < 96){ cx[tid] = px[tid]; cy[tid] = py[tid]; }
  __syncthreads();
  for (int it = 0; it <= 10; ++it){
    if (tid < NN){
      double bx = px[tid], by = py[tid];
      double best = 1e300; int bi = 0;
      for (int a = 0; a < 96; ++a){
        double dx = bx - cx[a], dy = by - cy[a];
        double d2 = dx*dx + dy*dy;
        if (d2 < best){ best = d2; bi = a; }
      }
      lab[tid] = bi;
    }
    __syncthreads();
    if (it == 10) break;
    if (tid < 96){
      int c = 0; double sx = 0.0, sy = 0.0;
      for (int i = 0; i < NN; ++i){
        if (lab[i] == tid){ c++; sx += px[i]; sy += py[i]; }
      }
      if (c > 0){ cx[tid] = sx/(double)c; cy[tid] = sy/(double)c; }
      else      { cx[tid] = px[tid];      cy[tid] = py[tid]; }
    }
    __syncthreads();
  }
  if (tid < NN) labels[g*NN + tid] = lab[tid];
}

// S = pos_alpha + neg_alpha (fp64 in, fp32 out)
__global__ void k_sg_alpha(const double* __restrict__ esym, const int* __restrict__ labels,
                           float* __restrict__ S){
  __shared__ int lbs[NN];
  int g = blockIdx.x, j = threadIdx.x;
  if (j < NN) lbs[j] = labels[g*NN + j];
  __syncthreads();
  const double* E = esym + (size_t)g*NN*NN;
  const double NEG = -100000000.0;
  int lj = lbs[j];
  double mp = -1e300, mn = -1e300;
  for (int i = 0; i < NN; ++i){
    double w = E[i*NN + j];
    bool sm = (lbs[i] == lj);
    double vp = sm ? w : w*NEG; vp = vp > 0.0 ? vp : 0.2*vp;
    double vn = sm ? w*NEG : w; vn = vn > 0.0 ? vn : 0.2*vn;
    mp = fmax(mp, vp); mn = fmax(mn, vn);
  }
  double sp = 0.0, sn = 0.0;
  for (int i = 0; i < NN; ++i){
    double w = E[i*NN + j];
    bool sm = (lbs[i] == lj);
    double vp = sm ? w : w*NEG; vp = vp > 0.0 ? vp : 0.2*vp;
    double vn = sm ? w*NEG : w; vn = vn > 0.0 ? vn : 0.2*vn;
    sp += exp(vp - mp); sn += exp(vn - mn);
  }
  float* So = S + (size_t)g*NN*NN;
  for (int i = 0; i < NN; ++i){
    double w = E[i*NN + j];
    bool sm = (lbs[i] == lj);
    double vp = sm ? w : w*NEG; vp = vp > 0.0 ? vp : 0.2*vp;
    double vn = sm ? w*NEG : w; vn = vn > 0.0 ? vn : 0.2*vn;
    So[i*NN + j] = (float)(exp(vp - mp)/sp + exp(vn - mn)/sn);
  }
}

// h_out[i,:] = sum_j S[i,j] * relu(h_in[j,:]) per group
__global__ __launch_bounds__(320) void k_sg_feat(const float* __restrict__ S,
                                                 const float* __restrict__ hin,
                                                 float* __restrict__ hout){
  int r = blockIdx.x;
  int g = r / NN, li = r - g*NN;
  int dh = threadIdx.x;
  const float* Srow = S + (size_t)g*NN*NN + (size_t)li*NN;
  const float* hb = hin + (size_t)g*NN*DH;
  float acc = 0.f;
  for (int j = 0; j < NN; ++j){
    float w = Srow[j];
    float x = hb[(size_t)j*DH + dh];
    acc += w*(x > 0.f ? x : 0.f);
  }
  hout[(size_t)r*DH + dh] = acc;
}

// ---------------- host ----------------

extern "C" void kernel_launch(void* const* d_in, const int* in_sizes, int n_in,
                              void* d_out, int out_size, void* d_ws, size_t ws_size,
                              hipStream_t stream){
  (void)n_in; (void)out_size; (void)ws_size;

  // ---- workspace layout (float offsets) ----
  float* ws = (float*)d_ws;
  float* inp   = ws;                       // 98304 (unused, kept for layout)
  float* gates = ws + 98304;               // 1966080 (enc hC alias + graph overlays)
  float* hA    = ws + 2064384;             // 491520
  float* hB    = ws + 2555904;             // 491520
  float* cD    = ws + 3047424;             // 491520
  float* traj  = ws + 3538944;             // 3072
  double* sself_d  = (double*)(ws + 3542016);
  double* sother_d = (double*)(ws + 3545088);
  double* darr_d   = (double*)(ws + 3548160);
  double* v1_d     = (double*)(ws + 3551232);
  int*    labels   = (int*)(ws + 3554304);
  // graph matrices overlay the (dead) gates buffer:
  double* edge_d = (double*)gates;             // 589824 f
  double* esym_d = (double*)(gates + 589824);  // 589824 f
  float*  Afull  = gates + 1179648;            // NG*ATILE = 294912 f
  float*  Smat   = gates;                      // S reuses edge_d space
  float*  hC     = gates;                      // encoder alt h buffer (BB*EHID)
  // fp32 parameter arena:
  float* a_traj = ws + 3555840;            // 61440
  float* a_z    = ws + 3617280;            // 512
  float* a_Wemb = ws + 3617792;            // 128
  float* a_bemb = ws + 3617920;            // 64
  float* a_Wihe = ws + 3617984;            // 65536  (permuted)
  float* a_Whhe = ws + 3683520;            // 262144 (permuted)
  float* a_bihe = ws + 3945664;            // 1024   (permuted bias sum)
  float* a_bhhe = ws + 3946688;            // 1024   (unused)
  float* a_Wihd = ws + 3947712;            // 81920  (permuted)
  float* a_Whhd = ws + 4029632;            // 409600 (permuted)
  float* a_bihd = ws + 4439232;            // 1280   (permuted bias sum)
  float* a_bhhd = ws + 4440512;            // 1280   (unused)
  float* a_Wout = ws + 4441792;            // 640
  float* a_bout = ws + 4442432;            // 64
  float* a_Wne  = ws + 4442496;            // 20480
  float* a_bne  = ws + 4462976;            // 64
  float* a_Watt = ws + 4463040;            // 128
  float* a_batt = ws + 4463168;            // 64
  int* cnt  = (int*)(ws + 4463232);
  int* flag = (int*)(ws + 4463233);
  (void)inp; (void)a_bhhe; (void)a_bhhd;

  const int EIG_LDS = 159248;
  hipFuncSetAttribute((const void*)k_sg_eigen,
                      hipFuncAttributeMaxDynamicSharedMemorySize, EIG_LDS);

  // ---- dtype probe ----
  k_zero_int<<<1, 64, 0, stream>>>(cnt, 2);
  k_probe<<<256, 256, 0, stream>>>((const unsigned short*)d_in[1], in_sizes[1], cnt);
  k_flag<<<1, 1, 0, stream>>>(cnt, flag);

  // ---- convert float inputs to fp32 ----
  CvtArgs ca;
  float* dsts[20] = { a_traj, hB, cD, a_z, a_Wemb, a_bemb, a_Wihe, a_Whhe, a_bihe,
                      a_bhhe, a_Wihd, a_Whhd, a_bihd, a_bhhd, a_Wout, a_bout,
                      a_Wne, a_bne, a_Watt, a_batt };
  for (int i = 0; i < 20; ++i){
    ca.src[i] = d_in[i];
    ca.dst[i] = dsts[i];
    ca.n[i]   = in_sizes[i];
  }
  k_convert<<<dim3(512, 20), 256, 0, stream>>>(ca, flag);

  // ---- interleaved (i,f,g,o)-per-state weight/bias permutes (overwrite slots) ----
  k_permw<<<(4*EHID*64   + 255)/256, 256, 0, stream>>>(d_in[6],  a_Wihe, EHID, 64,   flag);
  k_permw<<<(4*EHID*EHID + 255)/256, 256, 0, stream>>>(d_in[7],  a_Whhe, EHID, EHID, flag);
  k_permb<<<(4*EHID + 255)/256, 256, 0, stream>>>(d_in[8], d_in[9],  a_bihe, EHID, flag);
  k_permw<<<(4*DH*64     + 255)/256, 256, 0, stream>>>(d_in[10], a_Wihd, DH, 64, flag);
  k_permw<<<(4*DH*DH     + 255)/256, 256, 0, stream>>>(d_in[11], a_Whhd, DH, DH, flag);
  k_permb<<<(4*DH + 255)/256, 256, 0, stream>>>(d_in[12], d_in[13], a_bihd, DH, flag);

  // ---- encoder: 8 fused embed+gates+lstm steps, h ping-pong hB<->hC ----
  float* ecur = hB;
  float* eoth = hC;
  for (int t = 0; t < 8; ++t){
    k_gates_lstm<<<dim3(4*EHID/64, BB/64), 256, 0, stream>>>(
        a_traj + (size_t)t*BB*2, a_Wemb, a_bemb,
        a_Wihe, a_Whhe, a_bihe, ecur, eoth, cD, EHID);
    float* tmp = ecur; ecur = eoth; eoth = tmp;
  }
  // ecur == hB after 8 swaps

  // ---- decoder init (fused: concat + zero c + copy traj) ----
  k_decinit<<<(BB*DH+255)/256, 256, 0, stream>>>(ecur, a_z, a_traj + (size_t)7*BB*2,
                                                 hA, cD, traj);

  float* hcur = hA;
  float* hoth = hB;
  for (int i = 0; i < PRED; ++i){
    if (i == 4){
      k_sg_emb<<<BB, 64, 0, stream>>>(hcur, a_Wne, a_bne, a_Watt, sself_d, sother_d);
      k_sg_edgecol<<<NG, NN, 0, stream>>>(sself_d, sother_d, a_batt, edge_d);
      k_sg_symdsum<<<NG*NN, NN, 0, stream>>>(edge_d, esym_d, darr_d);
      k_sg_lsym<<<(NG*NN*NN+255)/256, 256, 0, stream>>>(esym_d, darr_d, Afull);
      k_sg_eigen<<<NG, 1024, EIG_LDS, stream>>>(Afull, darr_d, v1_d);
      k_sg_kmeans<<<NG, 256, 0, stream>>>(darr_d, v1_d, labels);
      k_sg_alpha<<<NG, NN, 0, stream>>>(esym_d, labels, Smat);
      k_sg_feat<<<BB, DH, 0, stream>>>(Smat, hcur, hoth);
      float* tmp = hcur; hcur = hoth; hoth = tmp;
    }
    k_gates_lstm<<<dim3(4*DH/64, BB/64), 256, 0, stream>>>(
        traj, a_Wemb, a_bemb,
        a_Wihd, a_Whhd, a_bihd, hcur, hoth, cD, DH);
    { float* tmp = hcur; hcur = hoth; hoth = tmp; }
    k_outproj<<<BB, 64, 0, stream>>>(hcur, a_Wout, a_bout, traj, d_out, i, flag);
  }
}